// Round 1
// baseline (4394.538 us; speedup 1.0000x reference)
//
#include <hip/hip_runtime.h>
#include <hip/hip_bf16.h>
#include <cstdint>
#include <cstddef>

typedef _Float16 f16;
typedef _Float16 f16x8 __attribute__((ext_vector_type(8)));
typedef float f32x4 __attribute__((ext_vector_type(4)));

#define B_   256
#define T_   512
#define V_   50000
#define D_   256
#define H_   256
#define A_   128
#define N4H  1024

__device__ __forceinline__ float sigmoid_f(float x) {
    return 1.f / (1.f + __expf(-x));
}
__device__ __forceinline__ float tanh_f(float x) {
    float ax = fabsf(x);
    float e  = __expf(-2.f * ax);
    float t  = (1.f - e) / (1.f + e);
    return copysignf(t, x);
}

// ---------------------------------------------------------------------------
// K0: weight transpose + fp32->fp16 cast.
//   WxT[n][k] = lstm_kernel[k][n]        (k<256)
//   WhT[n][k] = lstm_kernel[256+k][n]
//   WomT[a][h] = w_omega[h][a]
// grid 1152 x 256
// ---------------------------------------------------------------------------
__global__ __launch_bounds__(256) void k0_convert(
    const float* __restrict__ lstm_kernel, const float* __restrict__ w_omega,
    f16* __restrict__ WxT, f16* __restrict__ WhT, f16* __restrict__ WomT) {
    int blk = blockIdx.x;
    int tau = threadIdx.x;  // 0..255 (= k / h index)
    if (blk < N4H) {
        int n = blk;
        WxT[n * 256 + tau] = (f16)lstm_kernel[(size_t)tau * N4H + n];
        WhT[n * 256 + tau] = (f16)lstm_kernel[(size_t)(256 + tau) * N4H + n];
    } else {
        int a = blk - N4H;  // 0..127
        WomT[a * 256 + tau] = (f16)w_omega[(size_t)tau * A_ + a];
    }
}

// ---------------------------------------------------------------------------
// K1: seq_len[b] = sum_t (x[b,t] != 0)
// ---------------------------------------------------------------------------
__global__ __launch_bounds__(256) void k1_seqlen(
    const int* __restrict__ x, int* __restrict__ seqlen) {
    __shared__ int red[256];
    int b = blockIdx.x, tau = threadIdx.x;
    int cnt = (x[b * T_ + tau] != 0) + (x[b * T_ + tau + 256] != 0);
    red[tau] = cnt;
    __syncthreads();
    for (int s = 128; s > 0; s >>= 1) {
        if (tau < s) red[tau] += red[tau + s];
        __syncthreads();
    }
    if (tau == 0) seqlen[b] = red[0];
}

// ---------------------------------------------------------------------------
// K2: Zx[i][n] = embed[x[i]] @ Wx + bias, fp16 out.  i = b*Tc + (t - t0).
// BM=64 rows (full K=256 in LDS, gathered once), 8 N-passes of 128 cols,
// K streamed in 4 slices of 64 for the B tile.
// grid (B*Tc/64) x 256
// ---------------------------------------------------------------------------
__global__ __launch_bounds__(256) void k2_zx(
    const int* __restrict__ x, const float* __restrict__ embed,
    const f16* __restrict__ WxT, const float* __restrict__ bias,
    f16* __restrict__ Zx, int t0, int Tc) {
    __shared__ __align__(16) f16 A_s[64][264];   // [m][k], pad 8
    __shared__ __align__(16) f16 B_s[128][72];   // [n][k-slice], pad 8
    __shared__ int tok_s[64];

    int tau  = threadIdx.x;
    int bm   = blockIdx.x;
    int i0   = bm * 64;
    int wave = tau >> 6, lane = tau & 63;
    int q = lane >> 4, c = lane & 15;

    if (tau < 64) {
        int i  = i0 + tau;
        int bb = i / Tc, tr = i - bb * Tc;
        tok_s[tau] = x[bb * T_ + t0 + tr];
    }
    __syncthreads();

    // gather A: 64 rows x 256 f32 -> fp16 LDS. 4 threads/row, 16 float4 each.
    {
        int r = tau >> 2, quarter = tau & 3;
        const float4* src =
            (const float4*)(embed + (size_t)tok_s[r] * D_ + quarter * 64);
        f16* dst = &A_s[r][quarter * 64];
#pragma unroll
        for (int j = 0; j < 16; j++) {
            float4 v = src[j];
            dst[j * 4 + 0] = (f16)v.x;
            dst[j * 4 + 1] = (f16)v.y;
            dst[j * 4 + 2] = (f16)v.z;
            dst[j * 4 + 3] = (f16)v.w;
        }
    }

    for (int np = 0; np < 8; np++) {
        f32x4 acc[8];
#pragma unroll
        for (int ni = 0; ni < 8; ni++) acc[ni] = (f32x4){0.f, 0.f, 0.f, 0.f};

        for (int kt = 0; kt < 4; kt++) {
            __syncthreads();  // previous B_s consumers done
            {
                int n = tau >> 1, half = tau & 1;
                const f16x8* src = (const f16x8*)(WxT +
                    (size_t)(np * 128 + n) * 256 + kt * 64 + half * 32);
                f16x8* dst = (f16x8*)&B_s[n][half * 32];
#pragma unroll
                for (int j = 0; j < 4; j++) dst[j] = src[j];
            }
            __syncthreads();
#pragma unroll
            for (int s = 0; s < 2; s++) {
                f16x8 afrag =
                    *(const f16x8*)&A_s[wave * 16 + c][kt * 64 + s * 32 + q * 8];
#pragma unroll
                for (int ni = 0; ni < 8; ni++) {
                    f16x8 bfrag = *(const f16x8*)&B_s[ni * 16 + c][s * 32 + q * 8];
                    acc[ni] = __builtin_amdgcn_mfma_f32_16x16x32_f16(
                        afrag, bfrag, acc[ni], 0, 0, 0);
                }
            }
        }
        // epilogue for this n-pass
#pragma unroll
        for (int ni = 0; ni < 8; ni++) {
            int n   = np * 128 + ni * 16 + c;
            float bv = bias[n];
#pragma unroll
            for (int r = 0; r < 4; r++) {
                int row = i0 + wave * 16 + q * 4 + r;
                Zx[(size_t)row * N4H + n] = (f16)(acc[ni][r] + bv);
            }
        }
    }
}

// ---------------------------------------------------------------------------
// K3: persistent LSTM recurrence. 16 WGs x 1024 thr; WG owns 16 batch rows.
// Wave w owns hidden units [16w,16w+16); its 4 MFMA tiles are the 4 gates.
// h-tile double-buffered in LDS (A operand); Wh streamed from L2 (B operand).
// ---------------------------------------------------------------------------
__global__ __launch_bounds__(1024) void k3_lstm(
    const f16* __restrict__ Zx, const f16* __restrict__ WhT,
    const int* __restrict__ seqlen, f16* __restrict__ outs,
    f16* __restrict__ Hstate, float* __restrict__ Cstate,
    int t0, int Tc, int first, int last) {
    __shared__ __align__(16) f16 Zx_s[16][1032];     // [row][n], pad 8
    __shared__ __align__(16) f16 h_s[2][16][264];    // [parity][row][k], pad 8

    int tau  = threadIdx.x;
    int wave = tau >> 6, lane = tau & 63;
    int q = lane >> 4, c = lane & 15;
    int b0 = blockIdx.x * 16;
    int u  = wave * 16 + c;  // hidden unit

    if (first) {
        for (int idx = tau; idx < 2 * 16 * 264; idx += 1024)
            ((f16*)h_s)[idx] = (f16)0.f;
    } else {
        int parity = t0 & 1;
        for (int idx = tau; idx < 16 * 256; idx += 1024) {
            int r = idx >> 8, k = idx & 255;
            h_s[parity][r][k] = Hstate[(b0 + r) * H_ + k];
        }
    }

    float cst[4];
    int   sl[4];
#pragma unroll
    for (int r = 0; r < 4; r++) {
        int row = q * 4 + r;
        cst[r] = first ? 0.f : Cstate[(b0 + row) * H_ + u];
        sl[r]  = seqlen[b0 + row];
    }

    const f16* whbase = WhT + (size_t)u * 256;

    for (int tt = 0; tt < Tc; tt++) {
        int t  = t0 + tt;
        int pr = t & 1, pw = pr ^ 1;

        __syncthreads();  // prev iter's Zx_s reads + h_s writes complete
        {   // stage Zx row-slab for this step: 16 rows x 1024 f16
            int r = tau >> 6;
            int n = (lane) * 16;
            const f16x8* src =
                (const f16x8*)(Zx + ((size_t)(b0 + r) * Tc + tt) * N4H + n);
            f16x8* dst = (f16x8*)&Zx_s[r][n];
            dst[0] = src[0];
            dst[1] = src[1];
        }
        __syncthreads();

        // recurrent GEMM: 4 gate tiles, K=256
        f32x4 acc[4];
#pragma unroll
        for (int g = 0; g < 4; g++) acc[g] = (f32x4){0.f, 0.f, 0.f, 0.f};
#pragma unroll
        for (int kc = 0; kc < 8; kc++) {
            f16x8 afrag = *(const f16x8*)&h_s[pr][c][kc * 32 + q * 8];
#pragma unroll
            for (int g = 0; g < 4; g++) {
                f16x8 bfrag = *(const f16x8*)(whbase + (size_t)g * 65536 +
                                              kc * 32 + q * 8);
                acc[g] = __builtin_amdgcn_mfma_f32_16x16x32_f16(
                    afrag, bfrag, acc[g], 0, 0, 0);
            }
        }

        // gates + state update (C layout: col=c, row=q*4+r)
#pragma unroll
        for (int r = 0; r < 4; r++) {
            int row = q * 4 + r;
            float zi = acc[0][r] + (float)Zx_s[row][0 * 256 + u];
            float zj = acc[1][r] + (float)Zx_s[row][1 * 256 + u];
            float zf = acc[2][r] + (float)Zx_s[row][2 * 256 + u];
            float zo = acc[3][r] + (float)Zx_s[row][3 * 256 + u];
            float ig = sigmoid_f(zi);
            float jg = tanh_f(zj);
            float fg = sigmoid_f(zf + 1.f);
            float og = sigmoid_f(zo);
            float cn = cst[r] * fg + ig * jg;
            float hn = tanh_f(cn) * og;
            bool  m  = (t < sl[r]);
            cst[r]   = m ? cn : cst[r];
            float hold = (float)h_s[pr][row][u];
            h_s[pw][row][u] = (f16)(m ? hn : hold);
            outs[((size_t)(b0 + row) * T_ + t) * H_ + u] = (f16)(m ? hn : 0.f);
        }
    }

    if (!last) {
        __syncthreads();
        int parity = (t0 + Tc) & 1;
        for (int idx = tau; idx < 16 * 256; idx += 1024) {
            int r = idx >> 8, k = idx & 255;
            Hstate[(b0 + r) * H_ + k] = h_s[parity][r][k];
        }
#pragma unroll
        for (int r = 0; r < 4; r++)
            Cstate[(b0 + q * 4 + r) * H_ + u] = cst[r];
    }
}

// ---------------------------------------------------------------------------
// K4: attention + head. One WG (256 thr) per batch row.
// value GEMM via MFMA in 8 chunks of 64 t-rows, then softmax over T,
// weighted sum over outs, logits, 2-class softmax.
// ---------------------------------------------------------------------------
__global__ __launch_bounds__(256) void k4_attn(
    const f16* __restrict__ outs, const f16* __restrict__ WomT,
    const float* __restrict__ b_omega, const float* __restrict__ u_omega,
    const float* __restrict__ w, const float* __restrict__ bfin,
    float* __restrict__ out) {
    __shared__ __align__(16) f16 A_s[64][264];
    __shared__ __align__(16) f16 val_s[64][132];
    __shared__ float u_s[128];
    __shared__ float vu_s[512];
    __shared__ float red0[256], red1[256];

    int b = blockIdx.x, tau = threadIdx.x;
    int wave = tau >> 6, lane = tau & 63;
    int q = lane >> 4, c = lane & 15;

    if (tau < 128) u_s[tau] = u_omega[tau];
    float bom[8];
#pragma unroll
    for (int ni = 0; ni < 8; ni++) bom[ni] = b_omega[ni * 16 + c];

    for (int ch = 0; ch < 8; ch++) {
        int t0c = ch * 64;
        __syncthreads();  // protects A_s/val_s reuse (+ covers u_s init)
        {   // stage 64 rows of outs
            int r = tau >> 2, seg = tau & 3;
            const f16x8* src =
                (const f16x8*)(outs + ((size_t)b * T_ + t0c + r) * H_ + seg * 64);
            f16x8* dst = (f16x8*)&A_s[r][seg * 64];
#pragma unroll
            for (int j = 0; j < 8; j++) dst[j] = src[j];
        }
        __syncthreads();

        f32x4 acc[8];
#pragma unroll
        for (int ni = 0; ni < 8; ni++) acc[ni] = (f32x4){0.f, 0.f, 0.f, 0.f};
#pragma unroll
        for (int kc = 0; kc < 8; kc++) {
            f16x8 afrag = *(const f16x8*)&A_s[wave * 16 + c][kc * 32 + q * 8];
#pragma unroll
            for (int ni = 0; ni < 8; ni++) {
                f16x8 bfrag = *(const f16x8*)(WomT +
                    (size_t)(ni * 16 + c) * 256 + kc * 32 + q * 8);
                acc[ni] = __builtin_amdgcn_mfma_f32_16x16x32_f16(
                    afrag, bfrag, acc[ni], 0, 0, 0);
            }
        }
#pragma unroll
        for (int ni = 0; ni < 8; ni++) {
#pragma unroll
            for (int r = 0; r < 4; r++) {
                val_s[wave * 16 + q * 4 + r][ni * 16 + c] =
                    (f16)tanh_f(acc[ni][r] + bom[ni]);
            }
        }
        __syncthreads();
        if (tau < 64) {
            float s = 0.f;
#pragma unroll 8
            for (int a = 0; a < 128; a++) s += (float)val_s[tau][a] * u_s[a];
            vu_s[t0c + tau] = s;
        }
    }
    __syncthreads();

    // softmax over T=512
    red0[tau] = fmaxf(vu_s[tau], vu_s[tau + 256]);
    __syncthreads();
    for (int s = 128; s > 0; s >>= 1) {
        if (tau < s) red0[tau] = fmaxf(red0[tau], red0[tau + s]);
        __syncthreads();
    }
    float mx = red0[0];
    __syncthreads();
    float e0 = __expf(vu_s[tau] - mx), e1 = __expf(vu_s[tau + 256] - mx);
    red0[tau] = e0 + e1;
    __syncthreads();
    for (int s = 128; s > 0; s >>= 1) {
        if (tau < s) red0[tau] += red0[tau + s];
        __syncthreads();
    }
    float inv = 1.f / red0[0];
    __syncthreads();
    vu_s[tau]       = e0 * inv;
    vu_s[tau + 256] = e1 * inv;
    __syncthreads();

    // last[h] = sum_t alpha[t] * outs[b][t][h]   (tau = h)
    float lastv = 0.f;
#pragma unroll 4
    for (int t = 0; t < T_; t++)
        lastv += vu_s[t] * (float)outs[((size_t)b * T_ + t) * H_ + tau];

    // logits + 2-class softmax
    red0[tau] = lastv * w[tau * 2 + 0];
    red1[tau] = lastv * w[tau * 2 + 1];
    __syncthreads();
    for (int s = 128; s > 0; s >>= 1) {
        if (tau < s) {
            red0[tau] += red0[tau + s];
            red1[tau] += red1[tau + s];
        }
        __syncthreads();
    }
    if (tau == 0) {
        float l0 = red0[0] + bfin[0], l1 = red1[0] + bfin[1];
        float mm = fmaxf(l0, l1);
        float a0 = __expf(l0 - mm), a1 = __expf(l1 - mm);
        float den = a0 + a1;
        out[b * 2 + 0] = a0 / den;
        out[b * 2 + 1] = a1 / den;
    }
}

// ---------------------------------------------------------------------------
extern "C" void kernel_launch(void* const* d_in, const int* in_sizes, int n_in,
                              void* d_out, int out_size, void* d_ws,
                              size_t ws_size, hipStream_t stream) {
    const int*   x           = (const int*)d_in[0];
    const float* embed       = (const float*)d_in[1];
    const float* lstm_kernel = (const float*)d_in[2];
    const float* lstm_bias   = (const float*)d_in[3];
    const float* w_omega     = (const float*)d_in[4];
    const float* b_omega     = (const float*)d_in[5];
    const float* u_omega     = (const float*)d_in[6];
    const float* w           = (const float*)d_in[7];
    const float* bfin        = (const float*)d_in[8];
    float*       out         = (float*)d_out;

    char* ws = (char*)d_ws;
    f16*   WxT    = (f16*)(ws + 0);                     // 524288 B
    f16*   WhT    = (f16*)(ws + 524288);                // 524288 B
    f16*   WomT   = (f16*)(ws + 1048576);               // 65536 B
    int*   seqlen = (int*)(ws + 1114112);               // 1024 B
    f16*   Hstate = (f16*)(ws + 1115136);               // 131072 B
    float* Cstate = (float*)(ws + 1246208);             // 262144 B
    f16*   outs   = (f16*)(ws + 1508352);               // 67108864 B
    f16*   Zx     = (f16*)(ws + 1508352 + 67108864);

    const size_t fixed = 1508352ull + 67108864ull;
    int nch = 1;
    while (nch < 16 && fixed + 268435456ull / (size_t)nch > ws_size) nch <<= 1;
    int Tc = T_ / nch;

    k0_convert<<<1152, 256, 0, stream>>>(lstm_kernel, w_omega, WxT, WhT, WomT);
    k1_seqlen<<<256, 256, 0, stream>>>(x, seqlen);
    for (int chk = 0; chk < nch; chk++) {
        int t0 = chk * Tc;
        k2_zx<<<(B_ * Tc) / 64, 256, 0, stream>>>(x, embed, WxT, lstm_bias, Zx,
                                                  t0, Tc);
        k3_lstm<<<16, 1024, 0, stream>>>(Zx, WhT, seqlen, outs, Hstate, Cstate,
                                         t0, Tc, chk == 0 ? 1 : 0,
                                         chk == nch - 1 ? 1 : 0);
    }
    k4_attn<<<256, 256, 0, stream>>>(outs, WomT, b_omega, u_omega, w, bfin, out);
}

// Round 2
// 4028.912 us; speedup vs baseline: 1.0908x; 1.0908x over previous
//
#include <hip/hip_runtime.h>
#include <hip/hip_bf16.h>
#include <cstdint>
#include <cstddef>

typedef _Float16 f16;
typedef _Float16 f16x8 __attribute__((ext_vector_type(8)));
typedef float f32x4 __attribute__((ext_vector_type(4)));

#define B_   256
#define T_   512
#define V_   50000
#define D_   256
#define H_   256
#define A_   128
#define N4H  1024

__device__ __forceinline__ float sigmoid_f(float x) {
    return __builtin_amdgcn_rcpf(1.f + __expf(-x));
}
__device__ __forceinline__ float tanh_f(float x) {
    float e = __expf(-2.f * fabsf(x));
    float t = 1.f - 2.f * e * __builtin_amdgcn_rcpf(1.f + e);
    return copysignf(t, x);
}

// ---------------------------------------------------------------------------
// K0: weight transpose + fp32->fp16 cast.
// ---------------------------------------------------------------------------
__global__ __launch_bounds__(256) void k0_convert(
    const float* __restrict__ lstm_kernel, const float* __restrict__ w_omega,
    f16* __restrict__ WxT, f16* __restrict__ WhT, f16* __restrict__ WomT) {
    int blk = blockIdx.x;
    int tau = threadIdx.x;  // 0..255 (= k / h index)
    if (blk < N4H) {
        int n = blk;
        WxT[n * 256 + tau] = (f16)lstm_kernel[(size_t)tau * N4H + n];
        WhT[n * 256 + tau] = (f16)lstm_kernel[(size_t)(256 + tau) * N4H + n];
    } else {
        int a = blk - N4H;  // 0..127
        WomT[a * 256 + tau] = (f16)w_omega[(size_t)tau * A_ + a];
    }
}

// ---------------------------------------------------------------------------
// K1: seq_len[b] = sum_t (x[b,t] != 0)
// ---------------------------------------------------------------------------
__global__ __launch_bounds__(256) void k1_seqlen(
    const int* __restrict__ x, int* __restrict__ seqlen) {
    __shared__ int red[256];
    int b = blockIdx.x, tau = threadIdx.x;
    int cnt = (x[b * T_ + tau] != 0) + (x[b * T_ + tau + 256] != 0);
    red[tau] = cnt;
    __syncthreads();
    for (int s = 128; s > 0; s >>= 1) {
        if (tau < s) red[tau] += red[tau + s];
        __syncthreads();
    }
    if (tau == 0) seqlen[b] = red[0];
}

// ---------------------------------------------------------------------------
// K2: Zx[i][n] = embed[x[i]] @ Wx + bias, fp16 out.  i = b*Tc + (t - t0).
// ---------------------------------------------------------------------------
__global__ __launch_bounds__(256) void k2_zx(
    const int* __restrict__ x, const float* __restrict__ embed,
    const f16* __restrict__ WxT, const float* __restrict__ bias,
    f16* __restrict__ Zx, int t0, int Tc) {
    __shared__ __align__(16) f16 A_s[64][264];   // [m][k], pad 8
    __shared__ __align__(16) f16 B_s[128][72];   // [n][k-slice], pad 8
    __shared__ int tok_s[64];

    int tau  = threadIdx.x;
    int bm   = blockIdx.x;
    int i0   = bm * 64;
    int wave = tau >> 6, lane = tau & 63;
    int q = lane >> 4, c = lane & 15;

    if (tau < 64) {
        int i  = i0 + tau;
        int bb = i / Tc, tr = i - bb * Tc;
        tok_s[tau] = x[bb * T_ + t0 + tr];
    }
    __syncthreads();

    // gather A: 64 rows x 256 f32 -> fp16 LDS. 4 threads/row, 16 float4 each.
    {
        int r = tau >> 2, quarter = tau & 3;
        const float4* src =
            (const float4*)(embed + (size_t)tok_s[r] * D_ + quarter * 64);
        f16* dst = &A_s[r][quarter * 64];
#pragma unroll
        for (int j = 0; j < 16; j++) {
            float4 v = src[j];
            dst[j * 4 + 0] = (f16)v.x;
            dst[j * 4 + 1] = (f16)v.y;
            dst[j * 4 + 2] = (f16)v.z;
            dst[j * 4 + 3] = (f16)v.w;
        }
    }

    for (int np = 0; np < 8; np++) {
        f32x4 acc[8];
#pragma unroll
        for (int ni = 0; ni < 8; ni++) acc[ni] = (f32x4){0.f, 0.f, 0.f, 0.f};

        for (int kt = 0; kt < 4; kt++) {
            __syncthreads();  // previous B_s consumers done
            {
                int n = tau >> 1, half = tau & 1;
                const f16x8* src = (const f16x8*)(WxT +
                    (size_t)(np * 128 + n) * 256 + kt * 64 + half * 32);
                f16x8* dst = (f16x8*)&B_s[n][half * 32];
#pragma unroll
                for (int j = 0; j < 4; j++) dst[j] = src[j];
            }
            __syncthreads();
#pragma unroll
            for (int s = 0; s < 2; s++) {
                f16x8 afrag =
                    *(const f16x8*)&A_s[wave * 16 + c][kt * 64 + s * 32 + q * 8];
#pragma unroll
                for (int ni = 0; ni < 8; ni++) {
                    f16x8 bfrag = *(const f16x8*)&B_s[ni * 16 + c][s * 32 + q * 8];
                    acc[ni] = __builtin_amdgcn_mfma_f32_16x16x32_f16(
                        afrag, bfrag, acc[ni], 0, 0, 0);
                }
            }
        }
        // epilogue for this n-pass
#pragma unroll
        for (int ni = 0; ni < 8; ni++) {
            int n   = np * 128 + ni * 16 + c;
            float bv = bias[n];
#pragma unroll
            for (int r = 0; r < 4; r++) {
                int row = i0 + wave * 16 + q * 4 + r;
                Zx[(size_t)row * N4H + n] = (f16)(acc[ni][r] + bv);
            }
        }
    }
}

// ---------------------------------------------------------------------------
// K3: persistent LSTM recurrence. 16 WGs x 1024 thr; WG owns 16 batch rows.
// Software-pipelined: ONE barrier per step; Zx for step t+1 is global-loaded
// into registers right AFTER the barrier (so the compiler's vmcnt(0) drain at
// s_barrier doesn't expose the HBM latency) and consumed into the other
// Zx_s parity at the end of the same iteration, ~2.5k cycles later.
// ---------------------------------------------------------------------------
__global__ __launch_bounds__(1024) void k3_lstm(
    const f16* __restrict__ Zx, const f16* __restrict__ WhT,
    const int* __restrict__ seqlen, f16* __restrict__ outs,
    f16* __restrict__ Hstate, float* __restrict__ Cstate,
    int t0, int Tc, int first, int last) {
    __shared__ __align__(16) f16 Zx_s[2][16][1032];  // [parity][row][n], pad 8
    __shared__ __align__(16) f16 h_s[2][16][264];    // [parity][row][k], pad 8

    int tau  = threadIdx.x;
    int wave = tau >> 6, lane = tau & 63;
    int q = lane >> 4, c = lane & 15;
    int b0 = blockIdx.x * 16;
    int u  = wave * 16 + c;  // hidden unit

    if (first) {
        for (int idx = tau; idx < 2 * 16 * 264; idx += 1024)
            ((f16*)h_s)[idx] = (f16)0.f;
    } else {
        int parity = t0 & 1;
        for (int idx = tau; idx < 16 * 256; idx += 1024) {
            int r = idx >> 8, k = idx & 255;
            h_s[parity][r][k] = Hstate[(b0 + r) * H_ + k];
        }
    }

    float cst[4];
    int   sl[4];
#pragma unroll
    for (int r = 0; r < 4; r++) {
        int row = q * 4 + r;
        cst[r] = first ? 0.f : Cstate[(b0 + row) * H_ + u];
        sl[r]  = seqlen[b0 + row];
    }

    const f16* whbase = WhT + (size_t)u * 256;

    // staging geometry: thread tau stages 32 B of row (tau>>6), cols lane*16..
    int rstage = tau >> 6;
    int nstage = lane * 16;
    const f16* zxrow = Zx + (size_t)(b0 + rstage) * Tc * N4H + nstage;

    // prologue: fill Zx_s for step t0 (visibility covered by loop's barrier)
    {
        const f16x8* src = (const f16x8*)(zxrow);
        f16x8 z0 = src[0], z1 = src[1];
        f16x8* dst = (f16x8*)&Zx_s[t0 & 1][rstage][nstage];
        dst[0] = z0;
        dst[1] = z1;
    }

    for (int tt = 0; tt < Tc; tt++) {
        int t  = t0 + tt;
        int pr = t & 1, pw = pr ^ 1;

        __syncthreads();  // joins prev iter: h_s[pr] + Zx_s[pr] complete

        // issue prefetch for step tt+1 (after barrier: stays in flight
        // across the whole GEMM+gate phase of this iteration)
        int tn = (tt + 1 < Tc) ? tt + 1 : tt;
        const f16x8* psrc = (const f16x8*)(zxrow + (size_t)tn * N4H);
        f16x8 z0 = psrc[0];
        f16x8 z1 = psrc[1];

        // recurrent GEMM: 4 gate tiles, K=256
        f32x4 acc[4];
#pragma unroll
        for (int g = 0; g < 4; g++) acc[g] = (f32x4){0.f, 0.f, 0.f, 0.f};
#pragma unroll
        for (int kc = 0; kc < 8; kc++) {
            f16x8 afrag = *(const f16x8*)&h_s[pr][c][kc * 32 + q * 8];
#pragma unroll
            for (int g = 0; g < 4; g++) {
                f16x8 bfrag = *(const f16x8*)(whbase + (size_t)g * 65536 +
                                              kc * 32 + q * 8);
                acc[g] = __builtin_amdgcn_mfma_f32_16x16x32_f16(
                    afrag, bfrag, acc[g], 0, 0, 0);
            }
        }

        // gates + state update (C layout: col=c, row=q*4+r)
#pragma unroll
        for (int r = 0; r < 4; r++) {
            int row = q * 4 + r;
            float zi = acc[0][r] + (float)Zx_s[pr][row][0 * 256 + u];
            float zj = acc[1][r] + (float)Zx_s[pr][row][1 * 256 + u];
            float zf = acc[2][r] + (float)Zx_s[pr][row][2 * 256 + u];
            float zo = acc[3][r] + (float)Zx_s[pr][row][3 * 256 + u];
            float ig = sigmoid_f(zi);
            float jg = tanh_f(zj);
            float fg = sigmoid_f(zf + 1.f);
            float og = sigmoid_f(zo);
            float cn = cst[r] * fg + ig * jg;
            float hn = tanh_f(cn) * og;
            bool  m  = (t < sl[r]);
            cst[r]   = m ? cn : cst[r];
            float hold = (float)h_s[pr][row][u];
            h_s[pw][row][u] = (f16)(m ? hn : hold);
            outs[((size_t)(b0 + row) * T_ + t) * H_ + u] = (f16)(m ? hn : 0.f);
        }

        // consume prefetch into the other parity (no barrier in between:
        // the waitcnt lands here, ~2.5k cycles after issue)
        {
            f16x8* dst = (f16x8*)&Zx_s[pw][rstage][nstage];
            dst[0] = z0;
            dst[1] = z1;
        }
    }

    if (!last) {
        __syncthreads();
        int parity = (t0 + Tc) & 1;
        for (int idx = tau; idx < 16 * 256; idx += 1024) {
            int r = idx >> 8, k = idx & 255;
            Hstate[(b0 + r) * H_ + k] = h_s[parity][r][k];
        }
#pragma unroll
        for (int r = 0; r < 4; r++)
            Cstate[(b0 + q * 4 + r) * H_ + u] = cst[r];
    }
}

// ---------------------------------------------------------------------------
// K4: attention + head. One WG (256 thr) per batch row.
// ---------------------------------------------------------------------------
__global__ __launch_bounds__(256) void k4_attn(
    const f16* __restrict__ outs, const f16* __restrict__ WomT,
    const float* __restrict__ b_omega, const float* __restrict__ u_omega,
    const float* __restrict__ w, const float* __restrict__ bfin,
    float* __restrict__ out) {
    __shared__ __align__(16) f16 A_s[64][264];
    __shared__ __align__(16) f16 val_s[64][132];
    __shared__ float u_s[128];
    __shared__ float vu_s[512];
    __shared__ float red0[256], red1[256];

    int b = blockIdx.x, tau = threadIdx.x;
    int wave = tau >> 6, lane = tau & 63;
    int q = lane >> 4, c = lane & 15;

    if (tau < 128) u_s[tau] = u_omega[tau];
    float bom[8];
#pragma unroll
    for (int ni = 0; ni < 8; ni++) bom[ni] = b_omega[ni * 16 + c];

    for (int ch = 0; ch < 8; ch++) {
        int t0c = ch * 64;
        __syncthreads();  // protects A_s/val_s reuse (+ covers u_s init)
        {   // stage 64 rows of outs
            int r = tau >> 2, seg = tau & 3;
            const f16x8* src =
                (const f16x8*)(outs + ((size_t)b * T_ + t0c + r) * H_ + seg * 64);
            f16x8* dst = (f16x8*)&A_s[r][seg * 64];
#pragma unroll
            for (int j = 0; j < 8; j++) dst[j] = src[j];
        }
        __syncthreads();

        f32x4 acc[8];
#pragma unroll
        for (int ni = 0; ni < 8; ni++) acc[ni] = (f32x4){0.f, 0.f, 0.f, 0.f};
#pragma unroll
        for (int kc = 0; kc < 8; kc++) {
            f16x8 afrag = *(const f16x8*)&A_s[wave * 16 + c][kc * 32 + q * 8];
#pragma unroll
            for (int ni = 0; ni < 8; ni++) {
                f16x8 bfrag = *(const f16x8*)(WomT +
                    (size_t)(ni * 16 + c) * 256 + kc * 32 + q * 8);
                acc[ni] = __builtin_amdgcn_mfma_f32_16x16x32_f16(
                    afrag, bfrag, acc[ni], 0, 0, 0);
            }
        }
#pragma unroll
        for (int ni = 0; ni < 8; ni++) {
#pragma unroll
            for (int r = 0; r < 4; r++) {
                val_s[wave * 16 + q * 4 + r][ni * 16 + c] =
                    (f16)tanh_f(acc[ni][r] + bom[ni]);
            }
        }
        __syncthreads();
        if (tau < 64) {
            float s = 0.f;
#pragma unroll 8
            for (int a = 0; a < 128; a++) s += (float)val_s[tau][a] * u_s[a];
            vu_s[t0c + tau] = s;
        }
    }
    __syncthreads();

    // softmax over T=512
    red0[tau] = fmaxf(vu_s[tau], vu_s[tau + 256]);
    __syncthreads();
    for (int s = 128; s > 0; s >>= 1) {
        if (tau < s) red0[tau] = fmaxf(red0[tau], red0[tau + s]);
        __syncthreads();
    }
    float mx = red0[0];
    __syncthreads();
    float e0 = __expf(vu_s[tau] - mx), e1 = __expf(vu_s[tau + 256] - mx);
    red0[tau] = e0 + e1;
    __syncthreads();
    for (int s = 128; s > 0; s >>= 1) {
        if (tau < s) red0[tau] += red0[tau + s];
        __syncthreads();
    }
    float inv = 1.f / red0[0];
    __syncthreads();
    vu_s[tau]       = e0 * inv;
    vu_s[tau + 256] = e1 * inv;
    __syncthreads();

    // last[h] = sum_t alpha[t] * outs[b][t][h]   (tau = h)
    float lastv = 0.f;
#pragma unroll 4
    for (int t = 0; t < T_; t++)
        lastv += vu_s[t] * (float)outs[((size_t)b * T_ + t) * H_ + tau];

    // logits + 2-class softmax
    red0[tau] = lastv * w[tau * 2 + 0];
    red1[tau] = lastv * w[tau * 2 + 1];
    __syncthreads();
    for (int s = 128; s > 0; s >>= 1) {
        if (tau < s) {
            red0[tau] += red0[tau + s];
            red1[tau] += red1[tau + s];
        }
        __syncthreads();
    }
    if (tau == 0) {
        float l0 = red0[0] + bfin[0], l1 = red1[0] + bfin[1];
        float mm = fmaxf(l0, l1);
        float a0 = __expf(l0 - mm), a1 = __expf(l1 - mm);
        float den = a0 + a1;
        out[b * 2 + 0] = a0 / den;
        out[b * 2 + 1] = a1 / den;
    }
}

// ---------------------------------------------------------------------------
extern "C" void kernel_launch(void* const* d_in, const int* in_sizes, int n_in,
                              void* d_out, int out_size, void* d_ws,
                              size_t ws_size, hipStream_t stream) {
    const int*   x           = (const int*)d_in[0];
    const float* embed       = (const float*)d_in[1];
    const float* lstm_kernel = (const float*)d_in[2];
    const float* lstm_bias   = (const float*)d_in[3];
    const float* w_omega     = (const float*)d_in[4];
    const float* b_omega     = (const float*)d_in[5];
    const float* u_omega     = (const float*)d_in[6];
    const float* w           = (const float*)d_in[7];
    const float* bfin        = (const float*)d_in[8];
    float*       out         = (float*)d_out;

    char* ws = (char*)d_ws;
    f16*   WxT    = (f16*)(ws + 0);                     // 524288 B
    f16*   WhT    = (f16*)(ws + 524288);                // 524288 B
    f16*   WomT   = (f16*)(ws + 1048576);               // 65536 B
    int*   seqlen = (int*)(ws + 1114112);               // 1024 B
    f16*   Hstate = (f16*)(ws + 1115136);               // 131072 B
    float* Cstate = (float*)(ws + 1246208);             // 262144 B
    f16*   outs   = (f16*)(ws + 1508352);               // 67108864 B
    f16*   Zx     = (f16*)(ws + 1508352 + 67108864);

    const size_t fixed = 1508352ull + 67108864ull;
    int nch = 1;
    while (nch < 16 && fixed + 268435456ull / (size_t)nch > ws_size) nch <<= 1;
    int Tc = T_ / nch;

    k0_convert<<<1152, 256, 0, stream>>>(lstm_kernel, w_omega, WxT, WhT, WomT);
    k1_seqlen<<<256, 256, 0, stream>>>(x, seqlen);
    for (int chk = 0; chk < nch; chk++) {
        int t0 = chk * Tc;
        k2_zx<<<(B_ * Tc) / 64, 256, 0, stream>>>(x, embed, WxT, lstm_bias, Zx,
                                                  t0, Tc);
        k3_lstm<<<16, 1024, 0, stream>>>(Zx, WhT, seqlen, outs, Hstate, Cstate,
                                         t0, Tc, chk == 0 ? 1 : 0,
                                         chk == nch - 1 ? 1 : 0);
    }
    k4_attn<<<256, 256, 0, stream>>>(outs, WomT, b_omega, u_omega, w, bfin, out);
}

// Round 3
// 2122.820 us; speedup vs baseline: 2.0701x; 1.8979x over previous
//
#include <hip/hip_runtime.h>
#include <hip/hip_bf16.h>
#include <cstdint>
#include <cstddef>

typedef _Float16 f16;
typedef _Float16 f16x8 __attribute__((ext_vector_type(8)));
typedef float f32x4 __attribute__((ext_vector_type(4)));
typedef unsigned long long u64;

#define B_   256
#define T_   512
#define V_   50000
#define D_   256
#define H_   256
#define A_   128
#define N4H  1024

__device__ __forceinline__ float sigmoid_f(float x) {
    return __builtin_amdgcn_rcpf(1.f + __expf(-x));
}
__device__ __forceinline__ float tanh_f(float x) {
    float e = __expf(-2.f * fabsf(x));
    float t = 1.f - 2.f * e * __builtin_amdgcn_rcpf(1.f + e);
    return copysignf(t, x);
}

// ---------------------------------------------------------------------------
// K0: weight transpose + fp32->fp16 cast.
// ---------------------------------------------------------------------------
__global__ __launch_bounds__(256) void k0_convert(
    const float* __restrict__ lstm_kernel, const float* __restrict__ w_omega,
    f16* __restrict__ WxT, f16* __restrict__ WhT, f16* __restrict__ WomT) {
    int blk = blockIdx.x;
    int tau = threadIdx.x;  // 0..255 (= k / h index)
    if (blk < N4H) {
        int n = blk;
        WxT[n * 256 + tau] = (f16)lstm_kernel[(size_t)tau * N4H + n];
        WhT[n * 256 + tau] = (f16)lstm_kernel[(size_t)(256 + tau) * N4H + n];
    } else {
        int a = blk - N4H;  // 0..127
        WomT[a * 256 + tau] = (f16)w_omega[(size_t)tau * A_ + a];
    }
}

// ---------------------------------------------------------------------------
// K1: seq_len[b] = sum_t (x[b,t] != 0); block 0 also zeroes the k3 sync flags
// (agent-scope stores so k3's cache-bypassing reads on any XCD see them).
// ---------------------------------------------------------------------------
__global__ __launch_bounds__(256) void k1_seqlen(
    const int* __restrict__ x, int* __restrict__ seqlen, int* __restrict__ flags) {
    __shared__ int red[256];
    int b = blockIdx.x, tau = threadIdx.x;
    if (b == 0 && tau < 32)
        __hip_atomic_store(&flags[tau * 32], 0, __ATOMIC_RELAXED,
                           __HIP_MEMORY_SCOPE_AGENT);
    int cnt = (x[b * T_ + tau] != 0) + (x[b * T_ + tau + 256] != 0);
    red[tau] = cnt;
    __syncthreads();
    for (int s = 128; s > 0; s >>= 1) {
        if (tau < s) red[tau] += red[tau + s];
        __syncthreads();
    }
    if (tau == 0) seqlen[b] = red[0];
}

// ---------------------------------------------------------------------------
// K2: Zx[i][n'] = embed[x[i]] @ Wx + bias, fp16 out.  i = b*Tc + (t - t0).
// Columns written in pair-split layout: n' = half*512 + g*128 + u'
// (n = g*256 + half*128 + u'), so each k3 half-WG reads a contiguous 512.
// ---------------------------------------------------------------------------
__global__ __launch_bounds__(256) void k2_zx(
    const int* __restrict__ x, const float* __restrict__ embed,
    const f16* __restrict__ WxT, const float* __restrict__ bias,
    f16* __restrict__ Zx, int t0, int Tc) {
    __shared__ __align__(16) f16 A_s[64][264];   // [m][k], pad 8
    __shared__ __align__(16) f16 B_s[128][72];   // [n][k-slice], pad 8
    __shared__ int tok_s[64];

    int tau  = threadIdx.x;
    int bm   = blockIdx.x;
    int i0   = bm * 64;
    int wave = tau >> 6, lane = tau & 63;
    int q = lane >> 4, c = lane & 15;

    if (tau < 64) {
        int i  = i0 + tau;
        int bb = i / Tc, tr = i - bb * Tc;
        tok_s[tau] = x[bb * T_ + t0 + tr];
    }
    __syncthreads();

    // gather A: 64 rows x 256 f32 -> fp16 LDS. 4 threads/row, 16 float4 each.
    {
        int r = tau >> 2, quarter = tau & 3;
        const float4* src =
            (const float4*)(embed + (size_t)tok_s[r] * D_ + quarter * 64);
        f16* dst = &A_s[r][quarter * 64];
#pragma unroll
        for (int j = 0; j < 16; j++) {
            float4 v = src[j];
            dst[j * 4 + 0] = (f16)v.x;
            dst[j * 4 + 1] = (f16)v.y;
            dst[j * 4 + 2] = (f16)v.z;
            dst[j * 4 + 3] = (f16)v.w;
        }
    }

    for (int np = 0; np < 8; np++) {
        f32x4 acc[8];
#pragma unroll
        for (int ni = 0; ni < 8; ni++) acc[ni] = (f32x4){0.f, 0.f, 0.f, 0.f};

        for (int kt = 0; kt < 4; kt++) {
            __syncthreads();  // previous B_s consumers done
            {
                int n = tau >> 1, half = tau & 1;
                const f16x8* src = (const f16x8*)(WxT +
                    (size_t)(np * 128 + n) * 256 + kt * 64 + half * 32);
                f16x8* dst = (f16x8*)&B_s[n][half * 32];
#pragma unroll
                for (int j = 0; j < 4; j++) dst[j] = src[j];
            }
            __syncthreads();
#pragma unroll
            for (int s = 0; s < 2; s++) {
                f16x8 afrag =
                    *(const f16x8*)&A_s[wave * 16 + c][kt * 64 + s * 32 + q * 8];
#pragma unroll
                for (int ni = 0; ni < 8; ni++) {
                    f16x8 bfrag = *(const f16x8*)&B_s[ni * 16 + c][s * 32 + q * 8];
                    acc[ni] = __builtin_amdgcn_mfma_f32_16x16x32_f16(
                        afrag, bfrag, acc[ni], 0, 0, 0);
                }
            }
        }
        // epilogue for this n-pass (permuted column write)
#pragma unroll
        for (int ni = 0; ni < 8; ni++) {
            int n   = np * 128 + ni * 16 + c;
            int g   = n >> 8, rem = n & 255;
            int np2 = (rem >> 7) * 512 + g * 128 + (rem & 127);
            float bv = bias[n];
#pragma unroll
            for (int r = 0; r < 4; r++) {
                int row = i0 + wave * 16 + q * 4 + r;
                Zx[(size_t)row * N4H + np2] = (f16)(acc[ni][r] + bv);
            }
        }
    }
}

// ---------------------------------------------------------------------------
// K3: persistent LSTM, Wh REGISTER-RESIDENT. 32 WGs x 512 thr.
// Pair p = wgid>>1 owns batch rows [16p,16p+16); half = wgid&1 owns hidden
// units [128*half, 128*half+128) for all 4 gates. Each lane holds its 256 KB
// half-Wh slice as 32 f16x8 fragments (128 VGPRs), loaded once. Per step the
// halves exchange 16x128 fp16 h-slices through L3 via agent-scope atomics
// with a release/acquire step-counter flag (parity double-buffered).
// ---------------------------------------------------------------------------
__global__ __launch_bounds__(512, 2) void k3_lstm(
    const f16* __restrict__ Zx, const f16* __restrict__ WhT,
    const int* __restrict__ seqlen, f16* __restrict__ outs,
    f16* __restrict__ Hstate, float* __restrict__ Cstate,
    f16* __restrict__ Hex, int* __restrict__ flags,
    int t0, int Tc, int first, int last) {
    __shared__ __align__(16) f16 Zx_s[2][16][520];  // [parity][row][512 cols]
    __shared__ __align__(16) f16 h_s[2][16][264];   // [parity][row][k]

    int tau  = threadIdx.x;
    int w    = tau >> 6, lane = tau & 63;
    int q = lane >> 4, c = lane & 15;
    int wgid = blockIdx.x;
    int pair = wgid >> 1, half = wgid & 1;
    int b0 = pair * 16;
    int u0 = half * 128, pu0 = (half ^ 1) * 128;
    int u  = u0 + w * 16 + c;   // this lane's hidden unit
    int zu = w * 16 + c;        // column inside our 512-chunk (per gate)

    int* myflag = &flags[wgid * 32];
    int* pflag  = &flags[(wgid ^ 1) * 32];
    f16* hex_my = Hex + (size_t)wgid * 2 * 2048;         // [parity][16][128]
    f16* hex_pr = Hex + (size_t)(wgid ^ 1) * 2 * 2048;

    // ---- load register-resident Wh fragments (once) ----
    f16x8 whf[4][8];
#pragma unroll
    for (int g = 0; g < 4; g++)
#pragma unroll
        for (int kc = 0; kc < 8; kc++)
            whf[g][kc] = *(const f16x8*)(WhT +
                (size_t)(g * 256 + u0 + w * 16 + c) * 256 + kc * 32 + q * 8);

    // ---- init h_s ----
    if (first) {
        for (int idx = tau; idx < 2 * 16 * 264; idx += 512)
            ((f16*)h_s)[idx] = (f16)0.f;
    } else {
        int parity = t0 & 1;
        for (int idx = tau; idx < 16 * 256; idx += 512) {
            int r = idx >> 8, k = idx & 255;
            h_s[parity][r][k] = Hstate[(b0 + r) * H_ + k];
        }
    }

    float cst[4];
    int   sl[4];
#pragma unroll
    for (int r = 0; r < 4; r++) {
        int row = q * 4 + r;
        cst[r] = first ? 0.f : Cstate[(b0 + row) * H_ + u];
        sl[r]  = seqlen[b0 + row];
    }

    // Zx staging geometry: thread stages 32 B of row (tau>>5), cols (tau&31)*16
    int r_st = tau >> 5;
    int cc   = (tau & 31) * 16;
    const f16* zxrow = Zx + ((size_t)(b0 + r_st) * Tc) * N4H + half * 512 + cc;

    // prologue: fill Zx_s for step 0
    {
        const f16x8* src = (const f16x8*)zxrow;
        f16x8* dst = (f16x8*)&Zx_s[t0 & 1][r_st][cc];
        dst[0] = src[0];
        dst[1] = src[1];
    }
    // partner-read geometry: thread reads 8 B: row tau>>5, units (tau&31)*4
    int rr = tau >> 5;
    int uu = (tau & 31) * 4;

    __syncthreads();

    for (int tt = 0; tt < Tc; tt++) {
        int t  = t0 + tt;
        int pr = t & 1, pw = pr ^ 1;

        // prefetch Zx for step tt+1 (in flight across MFMA+gate phase)
        int tn = (tt + 1 < Tc) ? tt + 1 : tt;
        const f16x8* psrc = (const f16x8*)(zxrow + (size_t)tn * N4H);
        f16x8 z0 = psrc[0];
        f16x8 z1 = psrc[1];

        // recurrent GEMM: 4 gate tiles, K=256, B entirely in registers
        f32x4 acc[4];
#pragma unroll
        for (int g = 0; g < 4; g++) acc[g] = (f32x4){0.f, 0.f, 0.f, 0.f};
#pragma unroll
        for (int kc = 0; kc < 8; kc++) {
            f16x8 afrag = *(const f16x8*)&h_s[pr][c][kc * 32 + q * 8];
#pragma unroll
            for (int g = 0; g < 4; g++) {
                acc[g] = __builtin_amdgcn_mfma_f32_16x16x32_f16(
                    afrag, whf[g][kc], acc[g], 0, 0, 0);
            }
        }

        // gates + state update (C layout: col=c, row=q*4+r)
#pragma unroll
        for (int r = 0; r < 4; r++) {
            int row = q * 4 + r;
            float zi = acc[0][r] + (float)Zx_s[pr][row][0 * 128 + zu];
            float zj = acc[1][r] + (float)Zx_s[pr][row][1 * 128 + zu];
            float zf = acc[2][r] + (float)Zx_s[pr][row][2 * 128 + zu];
            float zo = acc[3][r] + (float)Zx_s[pr][row][3 * 128 + zu];
            float ig = sigmoid_f(zi);
            float jg = tanh_f(zj);
            float fg = sigmoid_f(zf + 1.f);
            float og = sigmoid_f(zo);
            float cn = cst[r] * fg + ig * jg;
            float hn = tanh_f(cn) * og;
            bool  m  = (t < sl[r]);
            cst[r]   = m ? cn : cst[r];
            float hold = (float)h_s[pr][row][u];
            f16 hkeep = (f16)(m ? hn : hold);
            // own half into LDS + exchange buffer (cache-bypassing store)
            h_s[pw][row][u] = hkeep;
            short hs = __builtin_bit_cast(short, hkeep);
            __hip_atomic_store((short*)(hex_my + pw * 2048 + row * 128 +
                                        (u - u0)),
                               hs, __ATOMIC_RELAXED, __HIP_MEMORY_SCOPE_AGENT);
            outs[((size_t)(b0 + row) * T_ + t) * H_ + u] = (f16)(m ? hn : 0.f);
        }

        // consume Zx prefetch into other parity
        {
            f16x8* dst = (f16x8*)&Zx_s[pw][r_st][cc];
            dst[0] = z0;
            dst[1] = z1;
        }

        __syncthreads();  // drains all lanes' hex stores (vmcnt(0) at barrier)

        if (tau == 0) {
            __hip_atomic_store(myflag, t + 1, __ATOMIC_RELEASE,
                               __HIP_MEMORY_SCOPE_AGENT);
            while (__hip_atomic_load(pflag, __ATOMIC_RELAXED,
                                     __HIP_MEMORY_SCOPE_AGENT) < t + 1)
                __builtin_amdgcn_s_sleep(1);
            __builtin_amdgcn_fence(__ATOMIC_ACQUIRE, "agent");
        }
        __syncthreads();

        // pull partner's h half from L3 (cache-bypassing 8-B loads)
        {
            u64 v = __hip_atomic_load(
                (const u64*)(hex_pr + pw * 2048 + rr * 128 + uu),
                __ATOMIC_RELAXED, __HIP_MEMORY_SCOPE_AGENT);
            *(u64*)&h_s[pw][rr][pu0 + uu] = v;
        }
        __syncthreads();  // h_s[pw] fully assembled for next step
    }

    if (!last) {
        int parity = (t0 + Tc) & 1;
        for (int idx = tau; idx < 16 * 128; idx += 512) {
            int r = idx >> 7, k = u0 + (idx & 127);
            Hstate[(b0 + r) * H_ + k] = h_s[parity][r][k];
        }
#pragma unroll
        for (int r = 0; r < 4; r++)
            Cstate[(b0 + q * 4 + r) * H_ + u] = cst[r];
    }
}

// ---------------------------------------------------------------------------
// K4: attention + head. One WG (256 thr) per batch row.
// ---------------------------------------------------------------------------
__global__ __launch_bounds__(256) void k4_attn(
    const f16* __restrict__ outs, const f16* __restrict__ WomT,
    const float* __restrict__ b_omega, const float* __restrict__ u_omega,
    const float* __restrict__ w, const float* __restrict__ bfin,
    float* __restrict__ out) {
    __shared__ __align__(16) f16 A_s[64][264];
    __shared__ __align__(16) f16 val_s[64][132];
    __shared__ float u_s[128];
    __shared__ float vu_s[512];
    __shared__ float red0[256], red1[256];

    int b = blockIdx.x, tau = threadIdx.x;
    int wave = tau >> 6, lane = tau & 63;
    int q = lane >> 4, c = lane & 15;

    if (tau < 128) u_s[tau] = u_omega[tau];
    float bom[8];
#pragma unroll
    for (int ni = 0; ni < 8; ni++) bom[ni] = b_omega[ni * 16 + c];

    for (int ch = 0; ch < 8; ch++) {
        int t0c = ch * 64;
        __syncthreads();  // protects A_s/val_s reuse (+ covers u_s init)
        {   // stage 64 rows of outs
            int r = tau >> 2, seg = tau & 3;
            const f16x8* src =
                (const f16x8*)(outs + ((size_t)b * T_ + t0c + r) * H_ + seg * 64);
            f16x8* dst = (f16x8*)&A_s[r][seg * 64];
#pragma unroll
            for (int j = 0; j < 8; j++) dst[j] = src[j];
        }
        __syncthreads();

        f32x4 acc[8];
#pragma unroll
        for (int ni = 0; ni < 8; ni++) acc[ni] = (f32x4){0.f, 0.f, 0.f, 0.f};
#pragma unroll
        for (int kc = 0; kc < 8; kc++) {
            f16x8 afrag = *(const f16x8*)&A_s[wave * 16 + c][kc * 32 + q * 8];
#pragma unroll
            for (int ni = 0; ni < 8; ni++) {
                f16x8 bfrag = *(const f16x8*)(WomT +
                    (size_t)(ni * 16 + c) * 256 + kc * 32 + q * 8);
                acc[ni] = __builtin_amdgcn_mfma_f32_16x16x32_f16(
                    afrag, bfrag, acc[ni], 0, 0, 0);
            }
        }
#pragma unroll
        for (int ni = 0; ni < 8; ni++) {
#pragma unroll
            for (int r = 0; r < 4; r++) {
                val_s[wave * 16 + q * 4 + r][ni * 16 + c] =
                    (f16)tanh_f(acc[ni][r] + bom[ni]);
            }
        }
        __syncthreads();
        if (tau < 64) {
            float s = 0.f;
#pragma unroll 8
            for (int a = 0; a < 128; a++) s += (float)val_s[tau][a] * u_s[a];
            vu_s[t0c + tau] = s;
        }
    }
    __syncthreads();

    // softmax over T=512
    red0[tau] = fmaxf(vu_s[tau], vu_s[tau + 256]);
    __syncthreads();
    for (int s = 128; s > 0; s >>= 1) {
        if (tau < s) red0[tau] = fmaxf(red0[tau], red0[tau + s]);
        __syncthreads();
    }
    float mx = red0[0];
    __syncthreads();
    float e0 = __expf(vu_s[tau] - mx), e1 = __expf(vu_s[tau + 256] - mx);
    red0[tau] = e0 + e1;
    __syncthreads();
    for (int s = 128; s > 0; s >>= 1) {
        if (tau < s) red0[tau] += red0[tau + s];
        __syncthreads();
    }
    float inv = 1.f / red0[0];
    __syncthreads();
    vu_s[tau]       = e0 * inv;
    vu_s[tau + 256] = e1 * inv;
    __syncthreads();

    // last[h] = sum_t alpha[t] * outs[b][t][h]   (tau = h)
    float lastv = 0.f;
#pragma unroll 4
    for (int t = 0; t < T_; t++)
        lastv += vu_s[t] * (float)outs[((size_t)b * T_ + t) * H_ + tau];

    // logits + 2-class softmax
    red0[tau] = lastv * w[tau * 2 + 0];
    red1[tau] = lastv * w[tau * 2 + 1];
    __syncthreads();
    for (int s = 128; s > 0; s >>= 1) {
        if (tau < s) {
            red0[tau] += red0[tau + s];
            red1[tau] += red1[tau + s];
        }
        __syncthreads();
    }
    if (tau == 0) {
        float l0 = red0[0] + bfin[0], l1 = red1[0] + bfin[1];
        float mm = fmaxf(l0, l1);
        float a0 = __expf(l0 - mm), a1 = __expf(l1 - mm);
        float den = a0 + a1;
        out[b * 2 + 0] = a0 / den;
        out[b * 2 + 1] = a1 / den;
    }
}

// ---------------------------------------------------------------------------
extern "C" void kernel_launch(void* const* d_in, const int* in_sizes, int n_in,
                              void* d_out, int out_size, void* d_ws,
                              size_t ws_size, hipStream_t stream) {
    const int*   x           = (const int*)d_in[0];
    const float* embed       = (const float*)d_in[1];
    const float* lstm_kernel = (const float*)d_in[2];
    const float* lstm_bias   = (const float*)d_in[3];
    const float* w_omega     = (const float*)d_in[4];
    const float* b_omega     = (const float*)d_in[5];
    const float* u_omega     = (const float*)d_in[6];
    const float* w           = (const float*)d_in[7];
    const float* bfin        = (const float*)d_in[8];
    float*       out         = (float*)d_out;

    char* ws = (char*)d_ws;
    f16*   WxT    = (f16*)(ws + 0);              //  524288 B
    f16*   WhT    = (f16*)(ws + 524288);         //  524288 B
    f16*   WomT   = (f16*)(ws + 1048576);        //   65536 B
    int*   seqlen = (int*)(ws + 1114112);        //    1024 B
    f16*   Hstate = (f16*)(ws + 1115136);        //  131072 B
    float* Cstate = (float*)(ws + 1246208);      //  262144 B
    f16*   Hex    = (f16*)(ws + 1508352);        //  262144 B (32 wg x 2 x 4KB)
    int*   flags  = (int*)(ws + 1770496);        //    4096 B (32 x 128 B)
    f16*   outs   = (f16*)(ws + 1774592);        // 67108864 B
    f16*   Zx     = (f16*)(ws + 1774592 + 67108864);

    const size_t fixed = 1774592ull + 67108864ull;
    int nch = 1;
    while (nch < 16 && fixed + 268435456ull / (size_t)nch > ws_size) nch <<= 1;
    int Tc = T_ / nch;

    k0_convert<<<1152, 256, 0, stream>>>(lstm_kernel, w_omega, WxT, WhT, WomT);
    k1_seqlen<<<256, 256, 0, stream>>>(x, seqlen, flags);
    for (int chk = 0; chk < nch; chk++) {
        int t0 = chk * Tc;
        k2_zx<<<(B_ * Tc) / 64, 256, 0, stream>>>(x, embed, WxT, lstm_bias, Zx,
                                                  t0, Tc);
        k3_lstm<<<32, 512, 0, stream>>>(Zx, WhT, seqlen, outs, Hstate, Cstate,
                                        Hex, flags, t0, Tc, chk == 0 ? 1 : 0,
                                        chk == nch - 1 ? 1 : 0);
    }
    k4_attn<<<256, 256, 0, stream>>>(outs, WomT, b_omega, u_omega, w, bfin, out);
}